// Round 2
// baseline (426.495 us; speedup 1.0000x reference)
//
#include <hip/hip_runtime.h>

// HorizontalWidthTokenPyramid: x[n,c,s,16,16] f32 -> out[n,c,s,31,4] f32
// One wave per slice; lane = r*4 + g (r=row 0..15, g=width-token 0..3).
// Each lane loads float4 = x[r][4g..4g+3]; hierarchical __shfl_xor(4/8/16/32)
// builds per-column sum/max over row spans 1,2,4,8,16; at each level a masked
// lane subset writes consecutive output floats.
//
// v2: persistent waves + grid-stride slice loop + next-slice prefetch.
// 2048 blocks x 256 thr = 8192 waves (8 blocks/CU -> full 32-wave occupancy);
// 262144 slices -> 32 slices/wave. Prefetch hides HBM latency behind the
// ~200-cycle compute body instead of one-shot waves draining the pipeline.

__global__ __launch_bounds__(256) void hwtp_kernel(const float* __restrict__ x,
                                                   float* __restrict__ out,
                                                   int num_slices) {
    const int lane      = threadIdx.x & 63;
    const int wave_id   = (blockIdx.x * blockDim.x + threadIdx.x) >> 6;
    const int num_waves = (gridDim.x * blockDim.x) >> 6;
    const int g         = lane & 3;

    const float4* __restrict__ xv = reinterpret_cast<const float4*>(x);

    int slice = wave_id;
    if (slice >= num_slices) return;

    float4 v = xv[(size_t)slice * 64 + lane];

    while (slice < num_slices) {
        const int next = slice + num_waves;
        float4 vn = make_float4(0.f, 0.f, 0.f, 0.f);
        if (next < num_slices)
            vn = xv[(size_t)next * 64 + lane];   // prefetch: in flight during compute

        float* __restrict__ o = out + (size_t)slice * 124;

        // running per-column sum/max over the current row span
        float s0 = v.x, s1 = v.y, s2 = v.z, s3 = v.w;
        float m0 = v.x, m1 = v.y, m2 = v.z, m3 = v.w;

        // ---- level b=16 (span=1): z = x + x ----
        {
            float z0 = s0 + m0, z1 = s1 + m1, z2 = s2 + m2, z3 = s3 + m3;
            float val = 0.25f * ((z0 + z1) + (z2 + z3))
                      + fmaxf(fmaxf(z0, z1), fmaxf(z2, z3));
            __builtin_nontemporal_store(val, &o[lane]);   // 64 consecutive floats
        }

#define REDUCE(mask)                                                     \
        s0 += __shfl_xor(s0, mask); s1 += __shfl_xor(s1, mask);          \
        s2 += __shfl_xor(s2, mask); s3 += __shfl_xor(s3, mask);          \
        m0 = fmaxf(m0, __shfl_xor(m0, mask));                            \
        m1 = fmaxf(m1, __shfl_xor(m1, mask));                            \
        m2 = fmaxf(m2, __shfl_xor(m2, mask));                            \
        m3 = fmaxf(m3, __shfl_xor(m3, mask));

#define TOKEN_VAL(inv_span, dst)                                         \
        {                                                                \
            float z0 = fmaf(s0, inv_span, m0);                           \
            float z1 = fmaf(s1, inv_span, m1);                           \
            float z2 = fmaf(s2, inv_span, m2);                           \
            float z3 = fmaf(s3, inv_span, m3);                           \
            dst = 0.25f * ((z0 + z1) + (z2 + z3))                        \
                + fmaxf(fmaxf(z0, z1), fmaxf(z2, z3));                   \
        }

        float val;

        // ---- level b=8 (span=2): rows {2j,2j+1} ----
        REDUCE(4)
        TOKEN_VAL(0.5f, val)
        if ((lane & 4) == 0)                       // r even; bin = r>>1 = lane>>3
            __builtin_nontemporal_store(val, &o[64 + ((lane >> 3) << 2) + g]);

        // ---- level b=4 (span=4) ----
        REDUCE(8)
        TOKEN_VAL(0.25f, val)
        if ((lane & 12) == 0)                      // r%4==0; bin = lane>>4
            __builtin_nontemporal_store(val, &o[96 + ((lane >> 4) << 2) + g]);

        // ---- level b=2 (span=8) ----
        REDUCE(16)
        TOKEN_VAL(0.125f, val)
        if ((lane & 28) == 0)                      // r%8==0; bin = lane>>5
            __builtin_nontemporal_store(val, &o[112 + ((lane >> 5) << 2) + g]);

        // ---- level b=1 (span=16) ----
        REDUCE(32)
        TOKEN_VAL(0.0625f, val)
        if (lane < 4)
            __builtin_nontemporal_store(val, &o[120 + g]);

#undef REDUCE
#undef TOKEN_VAL

        v = vn;
        slice = next;
    }
}

extern "C" void kernel_launch(void* const* d_in, const int* in_sizes, int n_in,
                              void* d_out, int out_size, void* d_ws, size_t ws_size,
                              hipStream_t stream) {
    const float* x = (const float*)d_in[0];
    float* out = (float*)d_out;

    const int num_slices = in_sizes[0] / 256;   // n*c*s, 256 floats/slice

    // 2048 blocks x 4 waves = 8192 persistent waves; 8 blocks/CU = 32 waves/CU.
    const int block = 256;
    int grid = 2048;
    const int max_grid = (num_slices * 64 + block - 1) / block;
    if (grid > max_grid) grid = max_grid;

    hwtp_kernel<<<grid, block, 0, stream>>>(x, out, num_slices);
}